// Round 2
// baseline (136.907 us; speedup 1.0000x reference)
//
#include <hip/hip_runtime.h>

// Problem constants (match reference)
constexpr int N    = 8192;     // nodes
constexpr int NE   = 131072;   // edges
constexpr int WPR  = N / 32;   // 256 u32 words per bitset row
constexpr int MAXD = 64;       // max raw out-degree (Poisson(16); P(>64)*N ~ 1e-15)

// f(k) = exp(-ALPHA*k), ALPHA = 2
#define F1 0.13533528323661270f   // e^-2
#define F2 0.018315638888734179f  // e^-4
#define F3 0.0024787521766663585f // e^-6

using bf16x8 = __attribute__((ext_vector_type(8))) short;
using f32x4  = __attribute__((ext_vector_type(4))) float;

__device__ __forceinline__ unsigned short f2bf(float f) {
    unsigned int u = __float_as_uint(f);
    u = (u + 0x7FFFu + ((u >> 16) & 1u)) >> 16;   // round-to-nearest-even
    return (unsigned short)u;
}

// ---------------------------------------------------------------------------
// Fused MLP on matrix cores. 16-row tiles, 512 blocks -> 2 blocks/CU so the
// per-layer fp32 W staging latency (L2-resident scalar loads) overlaps across
// two blocks (was 1 block/CU = 1 wave/SIMD, staging chain fully exposed).
// Each wave owns a 16x32 output tile (nh = wave id, t in {0,1}).
// Extra epilogue: angles also written to e1 (s1 buffer pre-initialized with
// angles so edges' atomicAdd accumulates enhanced = angles + step1 directly).
// Also zeroes cnt_g (32 KB across 512 blocks).
// C/D layout (m89-verified): col = lane&15, row = (lane>>4)*4 + reg.
// A: [m=lane&15][k=(lane>>4)*8+j];  B: [k=(lane>>4)*8+j][n=lane&15].
// ---------------------------------------------------------------------------
__global__ __launch_bounds__(256) void mlp_kernel(
    const float* __restrict__ X,
    const float* __restrict__ W0, const float* __restrict__ W1,
    const float* __restrict__ W2, const float* __restrict__ W3,
    float* __restrict__ angles, float* __restrict__ e1,
    uint4* __restrict__ cntz)
{
    __shared__ unsigned short Xb[16 * 136];
    __shared__ unsigned short Wt[128 * 136];
    __shared__ float part[4][16];

    const int tid  = threadIdx.x;
    const int row0 = blockIdx.x * 16;
    const int nh = tid >> 6, l = tid & 63;   // wave nh owns cols nh*32..+31
    const int lm = l & 15, lq = l >> 4;

    // zero cnt_g slice (32 KB across the 512 blocks; consumed next dispatch)
    if (tid < 4) {
        uint4 z; z.x = z.y = z.z = z.w = 0u;
        cntz[blockIdx.x * 4 + tid] = z;
    }

    // stage X (fp32 -> bf16): 16 rows x 128 = 512 float4, 2 per thread
    for (int q = tid; q < 512; q += 256) {
        float4 v = *(const float4*)&X[row0 * 128 + q * 4];
        ushort4 b;
        b.x = f2bf(v.x); b.y = f2bf(v.y); b.z = f2bf(v.z); b.w = f2bf(v.w);
        *(ushort4*)&Xb[(q >> 5) * 136 + (q & 31) * 4] = b;
    }

    for (int layer = 0; layer < 3; ++layer) {
        // stage W^T bf16 from fp32 global: thread owns (n, k0..k0+3);
        // loads coalesced along n (lanes span 256 B), b64 LDS store
        const float* __restrict__ W = (layer == 0) ? W0 : (layer == 1) ? W1 : W2;
        for (int it = 0; it < 16; ++it) {
            int flat = it * 256 + tid;          // 0..4095
            int n  = flat & 127;
            int k0 = (flat >> 7) << 2;          // 0,4,...,124
            ushort4 b;
            b.x = f2bf(W[(k0 + 0) * 128 + n]);
            b.y = f2bf(W[(k0 + 1) * 128 + n]);
            b.z = f2bf(W[(k0 + 2) * 128 + n]);
            b.w = f2bf(W[(k0 + 3) * 128 + n]);
            *(ushort4*)&Wt[n * 136 + k0] = b;
        }
        __syncthreads();   // Wt staged; Xb (stage or prev writeback) visible

        f32x4 acc[2];
#pragma unroll
        for (int t = 0; t < 2; ++t) acc[t] = (f32x4){0.f, 0.f, 0.f, 0.f};

#pragma unroll
        for (int kc = 0; kc < 4; ++kc) {
            bf16x8 a = *(const bf16x8*)&Xb[lm * 136 + kc * 32 + lq * 8];
#pragma unroll
            for (int t = 0; t < 2; ++t) {
                bf16x8 b = *(const bf16x8*)
                    &Wt[(nh * 32 + t * 16 + lm) * 136 + kc * 32 + lq * 8];
                acc[t] = __builtin_amdgcn_mfma_f32_16x16x32_bf16(a, b, acc[t], 0, 0, 0);
            }
        }

        // relu
#pragma unroll
        for (int t = 0; t < 2; ++t)
#pragma unroll
            for (int r = 0; r < 4; ++r) acc[t][r] = fmaxf(acc[t][r], 0.0f);

        __syncthreads();   // all waves done reading Xb/Wt before overwrite

        if (layer < 2) {
            // writeback h -> Xb (bf16), C-layout scatter (b16 stores)
#pragma unroll
            for (int t = 0; t < 2; ++t)
#pragma unroll
                for (int r = 0; r < 4; ++r)
                    Xb[(lq * 4 + r) * 136 + nh * 32 + t * 16 + lm] =
                        f2bf(acc[t][r]);
        } else {
            // fused W3 dot: partial over this wave's 32 cols, fp32
            float p[4] = {0.f, 0.f, 0.f, 0.f};
#pragma unroll
            for (int t = 0; t < 2; ++t) {
                float w3v = W3[nh * 32 + t * 16 + lm];
#pragma unroll
                for (int r = 0; r < 4; ++r) p[r] += acc[t][r] * w3v;
            }
#pragma unroll
            for (int r = 0; r < 4; ++r) {
                p[r] += __shfl_xor(p[r], 1, 64);
                p[r] += __shfl_xor(p[r], 2, 64);
                p[r] += __shfl_xor(p[r], 4, 64);
                p[r] += __shfl_xor(p[r], 8, 64);
            }
            if (lm == 0)
#pragma unroll
                for (int r = 0; r < 4; ++r)
                    part[nh][lq * 4 + r] = p[r];
            __syncthreads();
            if (tid < 16) {
                float v = part[0][tid] + part[1][tid] + part[2][tid] + part[3][tid];
                angles[row0 + tid] = v;
                e1[row0 + tid] = v;      // s1 buffer pre-init: e1 = angles + step1 after edges
            }
        }
    }
}

// ---------------------------------------------------------------------------
// Edge pass: raw CSR build (duplicates KEPT — every consumer is a set-union,
// so re-OR of a duplicate neighbor is idempotent) + hop-1 scatter over the
// RAW edge list (duplicates counted, per reference). e1 was pre-initialized
// with angles, so after this kernel e1[j] = angles[j] + step1[j] = enhanced.
// ---------------------------------------------------------------------------
__global__ void edges_kernel(const int* __restrict__ ei,
                             const float* __restrict__ angles,
                             float* __restrict__ e1,
                             int* __restrict__ cnt_g,
                             int* __restrict__ nbr_g)
{
    int e = blockIdx.x * blockDim.x + threadIdx.x;
    if (e < NE) {
        int r = ei[e];
        int c = ei[NE + e];
        int p = atomicAdd(&cnt_g[r], 1);
        if (p < MAXD) nbr_g[r * MAXD + p] = c;
        atomicAdd(&e1[r], F1 * angles[c]);
    }
}

// ---------------------------------------------------------------------------
// P2 row i = 2-hop union via CSR, built in a per-wave LDS bitmap.
// One wave per row, 4 rows/block. Build loop processes FOUR neighbors
// concurrently (lane = qq*16+sub). Readout/store widened to uint4 (lane l
// owns natural-order words 4l..4l+3 -> one 1 KB store/row). Sparse dot now
// gathers the single e1 array (= angles+s1). Epilogue writes e2 and
// es = e2 + s2 (so p3's tail is one read).
// ---------------------------------------------------------------------------
__global__ __launch_bounds__(256) void p2_kernel(
    const int* __restrict__ cnt_g, const int* __restrict__ nbr_g,
    unsigned int* __restrict__ P2,
    const float* __restrict__ angles, const float* __restrict__ e1,
    float* __restrict__ e2, float* __restrict__ es)
{
    __shared__ __align__(16) unsigned int bm[4][WPR];  // 4 KB: per-wave bitmap
    __shared__ int nbr[4][MAXD];
    __shared__ int nc[4][MAXD];

    const int wv  = threadIdx.x >> 6;
    const int l   = threadIdx.x & 63;
    const int i   = blockIdx.x * 4 + wv;
    const int qq  = l >> 4;      // which of 4 concurrent neighbors
    const int sub = l & 15;      // lane within the 16-lane group

#pragma unroll
    for (int s = 0; s < 4; ++s) bm[wv][s * 64 + l] = 0u;

    const int n = min(cnt_g[i], MAXD);
    if (l < n) {
        int m = nbr_g[i * MAXD + l];
        nbr[wv][l] = m;
        nc[wv][l]  = min(cnt_g[m], MAXD);
    }
    __syncthreads();

    for (int q0 = 0; q0 < n; q0 += 4) {
        int q = q0 + qq;
        int m = 0, c2 = 0;
        if (q < n) { m = nbr[wv][q]; c2 = nc[wv][q]; }
        for (int s = sub; s < c2; s += 16) {
            int id = nbr_g[m * MAXD + s];
            atomicOr(&bm[wv][id >> 5], 1u << (id & 31));
        }
    }
    __syncthreads();

    // readout: lane l owns words 4l..4l+3 (natural order), one uint4 store
    uint4 w4 = *(const uint4*)&bm[wv][4 * l];
    *(uint4*)&P2[(size_t)i * WPR + 4 * l] = w4;

    // sparse dot: ~4 set bits/lane -> ffs iterate, gather e1 on the fly
    float local = 0.0f;
    unsigned int wrd[4] = {w4.x, w4.y, w4.z, w4.w};
#pragma unroll
    for (int s = 0; s < 4; ++s) {
        unsigned int ww = wrd[s];
        const int base = (4 * l + s) * 32;
        while (ww) {
            int b = __ffs(ww) - 1;
            ww &= ww - 1;
            local += e1[base + b];
        }
    }
#pragma unroll
    for (int m = 1; m < 64; m <<= 1) local += __shfl_xor(local, m, 64);
    if (l == 0) {
        float e1i = e1[i];
        float s1i = e1i - angles[i];
        float s2v = s1i + F2 * local;
        e2[i] = e1i + s2v;
        es[i] = e1i + 2.0f * s2v;   // = e2 + s2
    }
}

// ---------------------------------------------------------------------------
// P3 row i (never materialized) = OR of P2 bitmap rows of i's neighbors.
// out[i] = es[i] + F3 * (P3[i] . e2)
// 512-thread blocks, 8 rows/block, one wave per row. e2 (32 KB) staged once
// per block in LDS. Neighbor bitmap rows read as ONE uint4/lane (1 KB per
// instruction, natural word order) -> 16 VMEM instrs/row instead of 64.
// Union bitmap parked in a 1 KB/wave LDS buffer; dense dot fetches its mask
// word via broadcast ds_read (8 consecutive words x 8 lanes each,
// conflict-free) instead of __shfl.
// ---------------------------------------------------------------------------
__global__ __launch_bounds__(512) void p3_kernel(
    const unsigned int* __restrict__ P2,
    const int* __restrict__ cnt_g, const int* __restrict__ nbr_g,
    const float* __restrict__ e2, const float* __restrict__ es,
    float* __restrict__ out)
{
    __shared__ float e2s[N];            // 32 KB
    __shared__ int nbr[8][MAXD];        // 2 KB
    __shared__ uint4 bmw[8][64];        // 8 KB: per-wave union bitmap

    const int tid = threadIdx.x;
    const int wv  = tid >> 6;
    const int l   = tid & 63;
    const int i   = blockIdx.x * 8 + wv;

    // stage e2 once per block (coalesced float4)
    for (int q = tid; q < N / 4; q += 512)
        *(float4*)&e2s[q * 4] = *(const float4*)&e2[q * 4];

    const int n = min(cnt_g[i], MAXD);
    if (l < n) nbr[wv][l] = nbr_g[i * MAXD + l];
    __syncthreads();

    // union of neighbor P2 rows: one uint4 load per neighbor (words 4l..4l+3)
    uint4 w; w.x = w.y = w.z = w.w = 0u;
    for (int q = 0; q < n; ++q) {
        const uint4* rowp = (const uint4*)(P2 + (size_t)nbr[wv][q] * WPR);
        uint4 r = rowp[l];
        w.x |= r.x; w.y |= r.y; w.z |= r.z; w.w |= r.w;
    }
    bmw[wv][l] = w;
    __syncthreads();   // publish union words for cross-lane mask fetch

    const unsigned int* bw = (const unsigned int*)&bmw[wv][0];
    float local = 0.0f;
#pragma unroll
    for (int c = 0; c < 32; ++c) {
        unsigned int wd  = bw[c * 8 + (l >> 3)];        // broadcast ds_read
        unsigned int nib = wd >> ((l & 7) * 4);
        float4 v = *(const float4*)&e2s[c * 256 + l * 4];
        local += (nib & 1u) ? v.x : 0.0f;
        local += (nib & 2u) ? v.y : 0.0f;
        local += (nib & 4u) ? v.z : 0.0f;
        local += (nib & 8u) ? v.w : 0.0f;
    }
#pragma unroll
    for (int m = 1; m < 64; m <<= 1) local += __shfl_xor(local, m, 64);
    if (l == 0)
        out[i] = es[i] + F3 * local;
}

// ---------------------------------------------------------------------------
// Launch (4 dispatches; cooperative launch fails under graph capture)
// ---------------------------------------------------------------------------
extern "C" void kernel_launch(void* const* d_in, const int* in_sizes, int n_in,
                              void* d_out, int out_size, void* d_ws, size_t ws_size,
                              hipStream_t stream)
{
    const float* coeffs = (const float*)d_in[0];
    const float* W0     = (const float*)d_in[1];
    const float* W1     = (const float*)d_in[2];
    const float* W2     = (const float*)d_in[3];
    const float* W3     = (const float*)d_in[4];
    const int*   ei     = (const int*)  d_in[5];
    float* out = (float*)d_out;

    char* ws = (char*)d_ws;
    // workspace layout (bytes)
    float*          angles = (float*)(ws + 0 * 32768);            // 32 KB
    float*          e2     = (float*)(ws + 1 * 32768);            // 32 KB
    float*          es     = (float*)(ws + 2 * 32768);            // 32 KB
    int*            nbr_g  = (int*)  (ws + (1u  << 20));          // 2 MB
    float*          e1     = (float*)(ws + (4u  << 20));          // 32 KB (init by mlp)
    int*            cnt_g  = (int*)  (ws + (4u  << 20) + 32768);  // 32 KB (zeroed by mlp)
    unsigned int*   P2     = (unsigned int*)(ws + (5u  << 20));   // 8 MB

    // 1) MFMA MLP (+ W conversion in-block, cnt zeroing, e1 init)
    mlp_kernel<<<N / 16, 256, 0, stream>>>(coeffs, W0, W1, W2, W3, angles, e1,
                                           (uint4*)cnt_g);

    // 2-4) graph side (raw CSR, no dedup needed)
    edges_kernel<<<NE / 256, 256, 0, stream>>>(ei, angles, e1, cnt_g, nbr_g);
    p2_kernel<<<N / 4, 256, 0, stream>>>(cnt_g, nbr_g, P2, angles, e1, e2, es);
    p3_kernel<<<N / 8, 512, 0, stream>>>(P2, cnt_g, nbr_g, e2, es, out);
}

// Round 3
// 116.936 us; speedup vs baseline: 1.1708x; 1.1708x over previous
//
#include <hip/hip_runtime.h>

// Problem constants (match reference)
constexpr int N    = 8192;     // nodes
constexpr int NE   = 131072;   // edges
constexpr int WPR  = N / 32;   // 256 u32 words per bitset row
constexpr int MAXD = 64;       // max raw out-degree (Poisson(16); P(>64)*N ~ 1e-15)

// f(k) = exp(-ALPHA*k), ALPHA = 2
#define F1 0.13533528323661270f   // e^-2
#define F2 0.018315638888734179f  // e^-4
#define F3 0.0024787521766663585f // e^-6

using bf16x8 = __attribute__((ext_vector_type(8))) short;
using f32x4  = __attribute__((ext_vector_type(4))) float;

__device__ __forceinline__ unsigned short f2bf(float f) {
    unsigned int u = __float_as_uint(f);
    u = (u + 0x7FFFu + ((u >> 16) & 1u)) >> 16;   // round-to-nearest-even
    return (unsigned short)u;
}

// ---------------------------------------------------------------------------
// Fused MLP on matrix cores (R1 form: 32-row tiles, 256 blocks = 1 block/CU;
// R2's 512-block variant doubled total W-staging work per CU — regressed).
//  - W fp32 [k][n] -> bf16 W^T LDS [n][k] staged per block per layer
//    (coalesced along n, b64 LDS stores, 2-way bank aliasing = free).
//  - epilogue writes angles AND e1 (e1 = angles pre-init; edges accumulates
//    enhanced = angles + step1 into it directly).
//  - zeroes cnt_g (32 KB across 256 blocks).
// C/D layout (m89-verified): col = lane&15, row = (lane>>4)*4 + reg.
// A: [m=lane&15][k=(lane>>4)*8+j];  B: [k=(lane>>4)*8+j][n=lane&15].
// ---------------------------------------------------------------------------
__global__ __launch_bounds__(256) void mlp_kernel(
    const float* __restrict__ X,
    const float* __restrict__ W0, const float* __restrict__ W1,
    const float* __restrict__ W2, const float* __restrict__ W3,
    float* __restrict__ angles, float* __restrict__ e1,
    uint4* __restrict__ cntz)
{
    __shared__ unsigned short Xb[32 * 136];
    __shared__ unsigned short Wt[128 * 136];
    __shared__ float part[2][32];

    const int tid  = threadIdx.x;
    const int row0 = blockIdx.x * 32;
    const int w  = tid >> 6, l = tid & 63;
    const int mt = w & 1, nh = w >> 1;
    const int lm = l & 15, lq = l >> 4;

    // zero cnt_g slice (32 KB across the 256 blocks; consumed next dispatch)
    if (tid < 8) {
        uint4 z; z.x = z.y = z.z = z.w = 0u;
        cntz[blockIdx.x * 8 + tid] = z;
    }

    // stage X (fp32 -> bf16), coalesced float4 reads, b64 stores
    for (int q = tid; q < 32 * 32; q += 256) {
        float4 v = *(const float4*)&X[row0 * 128 + q * 4];
        ushort4 b;
        b.x = f2bf(v.x); b.y = f2bf(v.y); b.z = f2bf(v.z); b.w = f2bf(v.w);
        *(ushort4*)&Xb[(q >> 5) * 136 + (q & 31) * 4] = b;
    }

    for (int layer = 0; layer < 3; ++layer) {
        // stage W^T bf16 from fp32 global: thread owns (n, k0..k0+3);
        // loads coalesced along n (lanes span 256 B), b64 LDS store
        const float* __restrict__ W = (layer == 0) ? W0 : (layer == 1) ? W1 : W2;
        for (int it = 0; it < 16; ++it) {
            int flat = it * 256 + tid;          // 0..4095
            int n  = flat & 127;
            int k0 = (flat >> 7) << 2;          // 0,4,...,124
            ushort4 b;
            b.x = f2bf(W[(k0 + 0) * 128 + n]);
            b.y = f2bf(W[(k0 + 1) * 128 + n]);
            b.z = f2bf(W[(k0 + 2) * 128 + n]);
            b.w = f2bf(W[(k0 + 3) * 128 + n]);
            *(ushort4*)&Wt[n * 136 + k0] = b;
        }
        __syncthreads();   // Wt staged; Xb (stage or prev writeback) visible

        f32x4 acc[4];
#pragma unroll
        for (int t = 0; t < 4; ++t) acc[t] = (f32x4){0.f, 0.f, 0.f, 0.f};

#pragma unroll
        for (int kc = 0; kc < 4; ++kc) {
            bf16x8 a = *(const bf16x8*)&Xb[(mt * 16 + lm) * 136 + kc * 32 + lq * 8];
#pragma unroll
            for (int t = 0; t < 4; ++t) {
                bf16x8 b = *(const bf16x8*)
                    &Wt[(nh * 64 + t * 16 + lm) * 136 + kc * 32 + lq * 8];
                acc[t] = __builtin_amdgcn_mfma_f32_16x16x32_bf16(a, b, acc[t], 0, 0, 0);
            }
        }

        // relu
#pragma unroll
        for (int t = 0; t < 4; ++t)
#pragma unroll
            for (int r = 0; r < 4; ++r) acc[t][r] = fmaxf(acc[t][r], 0.0f);

        __syncthreads();   // all waves done reading Xb/Wt before overwrite

        if (layer < 2) {
            // writeback h -> Xb (bf16), C-layout scatter (b16 stores)
#pragma unroll
            for (int t = 0; t < 4; ++t)
#pragma unroll
                for (int r = 0; r < 4; ++r)
                    Xb[(mt * 16 + lq * 4 + r) * 136 + nh * 64 + t * 16 + lm] =
                        f2bf(acc[t][r]);
        } else {
            // fused W3 dot: partial over this wave's 64 cols, fp32
            float p[4] = {0.f, 0.f, 0.f, 0.f};
#pragma unroll
            for (int t = 0; t < 4; ++t) {
                float w3v = W3[nh * 64 + t * 16 + lm];
#pragma unroll
                for (int r = 0; r < 4; ++r) p[r] += acc[t][r] * w3v;
            }
#pragma unroll
            for (int r = 0; r < 4; ++r) {
                p[r] += __shfl_xor(p[r], 1, 64);
                p[r] += __shfl_xor(p[r], 2, 64);
                p[r] += __shfl_xor(p[r], 4, 64);
                p[r] += __shfl_xor(p[r], 8, 64);
            }
            if (lm == 0)
#pragma unroll
                for (int r = 0; r < 4; ++r)
                    part[nh][mt * 16 + lq * 4 + r] = p[r];
            __syncthreads();
            if (tid < 32) {
                float v = part[0][tid] + part[1][tid];
                angles[row0 + tid] = v;
                e1[row0 + tid] = v;   // pre-init: e1 = angles + step1 after edges
            }
        }
    }
}

// ---------------------------------------------------------------------------
// Edge pass: raw CSR build (duplicates KEPT — every consumer is a set-union,
// so re-OR of a duplicate neighbor is idempotent) + hop-1 scatter over the
// RAW edge list (duplicates counted, per reference). e1 was pre-initialized
// with angles, so after this kernel e1[j] = angles[j] + step1[j] = enhanced.
// ---------------------------------------------------------------------------
__global__ void edges_kernel(const int* __restrict__ ei,
                             const float* __restrict__ angles,
                             float* __restrict__ e1,
                             int* __restrict__ cnt_g,
                             int* __restrict__ nbr_g)
{
    int e = blockIdx.x * blockDim.x + threadIdx.x;
    if (e < NE) {
        int r = ei[e];
        int c = ei[NE + e];
        int p = atomicAdd(&cnt_g[r], 1);
        if (p < MAXD) nbr_g[r * MAXD + p] = c;
        atomicAdd(&e1[r], F1 * angles[c]);
    }
}

// ---------------------------------------------------------------------------
// P2 row i = 2-hop union via CSR, built in a per-wave LDS bitmap.
// One wave per row, 4 rows/block. Build loop processes FOUR neighbors
// concurrently (lane = qq*16+sub): serial trips n -> ceil(n/4), all 64 lanes
// active.  PERMUTED readout: position 4l+s of the stored row holds bitmap
// word s*64+l (4 conflict-free ds_read_b32 + ONE uint4 store = 1 KB/wave).
// p3's uint4 load then directly yields the slot-uniform __shfl ownership —
// no LDS publish needed there. Sparse dot gathers the single e1 array.
// Epilogue writes e2 and es = e2 + s2.
// ---------------------------------------------------------------------------
__global__ __launch_bounds__(256) void p2_kernel(
    const int* __restrict__ cnt_g, const int* __restrict__ nbr_g,
    unsigned int* __restrict__ P2,
    const float* __restrict__ angles, const float* __restrict__ e1,
    float* __restrict__ e2, float* __restrict__ es)
{
    __shared__ __align__(16) unsigned int bm[4][WPR];  // 4 KB: per-wave bitmap
    __shared__ int nbr[4][MAXD];
    __shared__ int nc[4][MAXD];

    const int wv  = threadIdx.x >> 6;
    const int l   = threadIdx.x & 63;
    const int i   = blockIdx.x * 4 + wv;
    const int qq  = l >> 4;      // which of 4 concurrent neighbors
    const int sub = l & 15;      // lane within the 16-lane group

#pragma unroll
    for (int s = 0; s < 4; ++s) bm[wv][s * 64 + l] = 0u;

    const int n = min(cnt_g[i], MAXD);
    if (l < n) {
        int m = nbr_g[i * MAXD + l];
        nbr[wv][l] = m;
        nc[wv][l]  = min(cnt_g[m], MAXD);
    }
    __syncthreads();

    for (int q0 = 0; q0 < n; q0 += 4) {
        int q = q0 + qq;
        int m = 0, c2 = 0;
        if (q < n) { m = nbr[wv][q]; c2 = nc[wv][q]; }
        for (int s = sub; s < c2; s += 16) {
            int id = nbr_g[m * MAXD + s];
            atomicOr(&bm[wv][id >> 5], 1u << (id & 31));
        }
    }
    __syncthreads();

    // permuted readout: w[s] = word s*64+l; store as one uint4 at pos 4l
    unsigned int wrd[4];
#pragma unroll
    for (int s = 0; s < 4; ++s) wrd[s] = bm[wv][s * 64 + l];
    uint4 w4; w4.x = wrd[0]; w4.y = wrd[1]; w4.z = wrd[2]; w4.w = wrd[3];
    *(uint4*)&P2[(size_t)i * WPR + 4 * l] = w4;

    // sparse dot: ~4 set bits/lane -> ffs iterate, gather e1 on the fly
    float local = 0.0f;
#pragma unroll
    for (int s = 0; s < 4; ++s) {
        unsigned int ww = wrd[s];
        const int base = (s * 64 + l) * 32;
        while (ww) {
            int b = __ffs(ww) - 1;
            ww &= ww - 1;
            local += e1[base + b];
        }
    }
#pragma unroll
    for (int m = 1; m < 64; m <<= 1) local += __shfl_xor(local, m, 64);
    if (l == 0) {
        float e1i = e1[i];
        float s1i = e1i - angles[i];
        float s2v = s1i + F2 * local;
        e2[i] = e1i + s2v;
        es[i] = e1i + 2.0f * s2v;   // = e2 + s2
    }
}

// ---------------------------------------------------------------------------
// P3 row i (never materialized) = OR of P2 bitmap rows of i's neighbors.
// out[i] = es[i] + F3 * (P3[i] . e2)
// 512-thread blocks, 8 rows/block, one wave per row. e2 (32 KB) staged once
// per block in LDS (34 KB total -> 4 blocks/CU = 32 waves/CU). Neighbor
// bitmap rows read as ONE uint4/lane (1 KB/instr; 16 VMEM per row instead of
// 64). Thanks to p2's permuted layout, slot s of the uint4 is word s*64+l,
// so the mask word for chunk c is a single slot-uniform __shfl.
// ---------------------------------------------------------------------------
__global__ __launch_bounds__(512) void p3_kernel(
    const unsigned int* __restrict__ P2,
    const int* __restrict__ cnt_g, const int* __restrict__ nbr_g,
    const float* __restrict__ e2, const float* __restrict__ es,
    float* __restrict__ out)
{
    __shared__ float e2s[N];         // 32 KB
    __shared__ int nbr[8][MAXD];     // 2 KB

    const int tid = threadIdx.x;
    const int wv  = tid >> 6;
    const int l   = tid & 63;
    const int i   = blockIdx.x * 8 + wv;

    // stage e2 once per block (coalesced float4)
    for (int q = tid; q < N / 4; q += 512)
        *(float4*)&e2s[q * 4] = *(const float4*)&e2[q * 4];

    const int n = min(cnt_g[i], MAXD);
    if (l < n) nbr[wv][l] = nbr_g[i * MAXD + l];
    __syncthreads();

    // union of neighbor P2 rows: one uint4 load per neighbor
    unsigned int w[4] = {0u, 0u, 0u, 0u};
    for (int q = 0; q < n; ++q) {
        const uint4* rowp = (const uint4*)(P2 + (size_t)nbr[wv][q] * WPR);
        uint4 r = rowp[l];
        w[0] |= r.x; w[1] |= r.y; w[2] |= r.z; w[3] |= r.w;
    }

    float local = 0.0f;
#pragma unroll
    for (int c = 0; c < 32; ++c) {
        unsigned int wd  = __shfl(w[c >> 3], ((c & 7) << 3) | (l >> 3), 64);
        unsigned int nib = wd >> ((l & 7) * 4);
        float4 v = *(const float4*)&e2s[c * 256 + l * 4];
        local += (nib & 1u) ? v.x : 0.0f;
        local += (nib & 2u) ? v.y : 0.0f;
        local += (nib & 4u) ? v.z : 0.0f;
        local += (nib & 8u) ? v.w : 0.0f;
    }
#pragma unroll
    for (int m = 1; m < 64; m <<= 1) local += __shfl_xor(local, m, 64);
    if (l == 0)
        out[i] = es[i] + F3 * local;
}

// ---------------------------------------------------------------------------
// Launch (4 dispatches; cooperative launch fails under graph capture)
// ---------------------------------------------------------------------------
extern "C" void kernel_launch(void* const* d_in, const int* in_sizes, int n_in,
                              void* d_out, int out_size, void* d_ws, size_t ws_size,
                              hipStream_t stream)
{
    const float* coeffs = (const float*)d_in[0];
    const float* W0     = (const float*)d_in[1];
    const float* W1     = (const float*)d_in[2];
    const float* W2     = (const float*)d_in[3];
    const float* W3     = (const float*)d_in[4];
    const int*   ei     = (const int*)  d_in[5];
    float* out = (float*)d_out;

    char* ws = (char*)d_ws;
    // workspace layout (bytes)
    float*          angles = (float*)(ws + 0 * 32768);            // 32 KB
    float*          e2     = (float*)(ws + 1 * 32768);            // 32 KB
    float*          es     = (float*)(ws + 2 * 32768);            // 32 KB
    int*            nbr_g  = (int*)  (ws + (1u  << 20));          // 2 MB
    float*          e1     = (float*)(ws + (4u  << 20));          // 32 KB (init by mlp)
    int*            cnt_g  = (int*)  (ws + (4u  << 20) + 32768);  // 32 KB (zeroed by mlp)
    unsigned int*   P2     = (unsigned int*)(ws + (5u  << 20));   // 8 MB

    // 1) MFMA MLP (+ W conversion in-block, cnt zeroing, e1 init)
    mlp_kernel<<<N / 32, 256, 0, stream>>>(coeffs, W0, W1, W2, W3, angles, e1,
                                           (uint4*)cnt_g);

    // 2-4) graph side (raw CSR, no dedup needed)
    edges_kernel<<<NE / 256, 256, 0, stream>>>(ei, angles, e1, cnt_g, nbr_g);
    p2_kernel<<<N / 4, 256, 0, stream>>>(cnt_g, nbr_g, P2, angles, e1, e2, es);
    p3_kernel<<<N / 8, 512, 0, stream>>>(P2, cnt_g, nbr_g, e2, es, out);
}